// Round 5
// baseline (1654.055 us; speedup 1.0000x reference)
//
#include <hip/hip_runtime.h>

#define N_NODES 50000
#define D_IN 256
#define D_OUT 128
#define N_POS 1600000
#define N_PRED 500000

#define G_BUCKETS 782        // ceil(50000/64) buckets of 64 nodes
#define GPAD 1024
#define SB 512               // scatter blocks
#define CHUNK 3125           // SB*CHUNK == N_POS exactly

typedef __attribute__((ext_vector_type(8))) short short8;
typedef __attribute__((ext_vector_type(4))) float f32x4;

// ---- bf16 helpers (RNE) ----
__device__ __forceinline__ unsigned short f2bf(float f) {
    unsigned int u = __float_as_uint(f);
    u += 0x7FFFu + ((u >> 16) & 1u);
    return (unsigned short)(u >> 16);
}
__device__ __forceinline__ unsigned int pk2(float a, float b) {   // bf16(a) | bf16(b)<<16
    unsigned int ua = __float_as_uint(a), ub = __float_as_uint(b);
    ua += 0x7FFFu + ((ua >> 16) & 1u);
    ub += 0x7FFFu + ((ub >> 16) & 1u);
    return (ua >> 16) | (ub & 0xFFFF0000u);
}
__device__ __forceinline__ float bflo(unsigned int u) { return __uint_as_float(u << 16); }
__device__ __forceinline__ float bfhi(unsigned int u) { return __uint_as_float(u & 0xFFFF0000u); }

// ------- Wf = W1@Wc packed into MFMA B-fragment layout; bf = b1@Wc -------
__global__ void fuse_weights_k(const float* __restrict__ W1, const float* __restrict__ Wc,
                               const float* __restrict__ b1,
                               unsigned short* __restrict__ Bp, float* __restrict__ bf) {
    int gid = blockIdx.x * blockDim.x + threadIdx.x;   // 0..32767
    int k = gid >> 7;          // K dim
    int n = gid & 127;         // N dim
    float acc = 0.f;
    #pragma unroll 4
    for (int kk = 0; kk < D_IN; ++kk)
        acc += W1[k * D_IN + kk] * Wc[kk * D_OUT + n];
    int ks = k >> 5, q = (k >> 3) & 3, jj = k & 7;
    int nt = n >> 4, nl = n & 15;
    int lane = q * 16 + nl;
    Bp[(((long)(ks * 8 + nt)) * 64 + lane) * 8 + jj] = f2bf(acc);
    if (gid < D_OUT) {
        float accb = 0.f;
        for (int kk = 0; kk < D_IN; ++kk)
            accb += b1[kk] * Wc[kk * D_OUT + gid];
        bf[gid] = accb;
    }
}

// ---------------- misc small kernels ----------------
__global__ void zero_int_k(int* __restrict__ p, int n) {
    int i = blockIdx.x * blockDim.x + threadIdx.x;
    if (i < n) p[i] = 0;
}

__global__ void count_k(const int* __restrict__ col, int* __restrict__ cnt) {
    int e = blockIdx.x * blockDim.x + threadIdx.x;
    if (e < N_POS) atomicAdd(&cnt[col[e]], 1);
}

__global__ void dinv_k(const int* __restrict__ cnt, float* __restrict__ dinv) {
    int v = blockIdx.x * blockDim.x + threadIdx.x;
    if (v < N_NODES) dinv[v] = rsqrtf((float)cnt[v] + 1.0f);   // +1 = self loop
}

// ---------------- bucket partition ----------------
__global__ __launch_bounds__(256) void bucket_count_k(const int* __restrict__ col,
                                                      int* __restrict__ bcnt) {
    __shared__ int hist[GPAD];
    int t = threadIdx.x;
    for (int i = t; i < GPAD; i += 256) hist[i] = 0;
    __syncthreads();
    int e0 = blockIdx.x * CHUNK;
    for (int i = t; i < CHUNK; i += 256)
        atomicAdd(&hist[col[e0 + i] >> 6], 1);
    __syncthreads();
    for (int g = t; g < G_BUCKETS; g += 256) {
        int c = hist[g];
        if (c) atomicAdd(&bcnt[g], c);
    }
}

__global__ __launch_bounds__(1024) void scan_bucket_k(const int* __restrict__ bcnt,
                                                      int* __restrict__ boffs,
                                                      int* __restrict__ bfill) {
    __shared__ int s[1024];
    int t = threadIdx.x;
    int v = (t < G_BUCKETS) ? bcnt[t] : 0;
    s[t] = v;
    __syncthreads();
    for (int d = 1; d < 1024; d <<= 1) {
        int add = (t >= d) ? s[t - d] : 0;
        __syncthreads();
        s[t] += add;
        __syncthreads();
    }
    int ex = s[t] - v;
    if (t < G_BUCKETS) { boffs[t] = ex; bfill[t] = ex; }
    if (t == G_BUCKETS - 1) boffs[G_BUCKETS] = ex + v;
}

// bin chunk edges by bucket in LDS, write out bucket-contiguous bursts
__global__ __launch_bounds__(256) void bucket_scatter_k(const int* __restrict__ row,
                                                        const int* __restrict__ col,
                                                        int* __restrict__ bfill,
                                                        unsigned int* __restrict__ eb) {
    __shared__ int hist[GPAD];
    __shared__ int lofs[GPAD];
    __shared__ int fill2[GPAD];
    __shared__ int base[GPAD];
    __shared__ int part[256];
    __shared__ unsigned int stag[CHUNK];
    int t = threadIdx.x;
    for (int i = t; i < GPAD; i += 256) { hist[i] = 0; fill2[i] = 0; }
    __syncthreads();
    int e0 = blockIdx.x * CHUNK;
    for (int i = t; i < CHUNK; i += 256)
        atomicAdd(&hist[col[e0 + i] >> 6], 1);
    __syncthreads();
    // exclusive scan of hist (GPAD entries, 4 per thread)
    int h[4], p4 = 0;
    #pragma unroll
    for (int i = 0; i < 4; ++i) { h[i] = hist[4 * t + i]; p4 += h[i]; }
    part[t] = p4;
    __syncthreads();
    for (int d = 1; d < 256; d <<= 1) {
        int add = (t >= d) ? part[t - d] : 0;
        __syncthreads();
        part[t] += add;
        __syncthreads();
    }
    int ex = part[t] - p4;
    #pragma unroll
    for (int i = 0; i < 4; ++i) { lofs[4 * t + i] = ex; ex += h[i]; }
    __syncthreads();
    // reserve global segment space per bucket
    for (int g = t; g < G_BUCKETS; g += 256) {
        int c = hist[g];
        base[g] = c ? atomicAdd(&bfill[g], c) : 0;
    }
    // stage edges grouped by bucket (order within bucket arbitrary)
    for (int i = t; i < CHUNK; i += 256) {
        int c = col[e0 + i];
        int g = c >> 6;
        unsigned int u = (unsigned int)row[e0 + i] | ((unsigned int)(c & 63) << 16)
                       | ((unsigned int)g << 22);
        int lp = atomicAdd(&fill2[g], 1);
        stag[lofs[g] + lp] = u;
    }
    __syncthreads();
    // bucket-contiguous write-out
    for (int i = t; i < CHUNK; i += 256) {
        unsigned int u = stag[i];
        int g = u >> 22;
        eb[base[g] + (i - lofs[g])] = u;
    }
}

// ---------------- MFMA GEMM: hs = bf16( dinv[v] * (x @ Wf + bf) ) ----------------
__global__ __launch_bounds__(256) void gemm_mfma_k(const float* __restrict__ x,
                                                   const uint4* __restrict__ Bp,
                                                   const float* __restrict__ bf,
                                                   const float* __restrict__ dinv,
                                                   unsigned short* __restrict__ hsb) {
    __shared__ unsigned short ot[4][16 * 128];   // 16 KB epilogue staging
    const int wave = threadIdx.x >> 6;
    const int lane = threadIdx.x & 63;
    const int q    = lane >> 4;
    const int ml   = lane & 15;
    const int m0   = blockIdx.x * 64 + wave * 16;

    f32x4 acc[8];
    #pragma unroll
    for (int t = 0; t < 8; ++t) acc[t] = (f32x4){0.f, 0.f, 0.f, 0.f};

    long arow = m0 + ml; if (arow > N_NODES - 1) arow = N_NODES - 1;
    const float* xrow = x + arow * D_IN + q * 8;

    #pragma unroll
    for (int ks = 0; ks < 8; ++ks) {
        float4 xa = *(const float4*)(xrow + ks * 32);
        float4 xb = *(const float4*)(xrow + ks * 32 + 4);
        union { short8 s; unsigned int u[4]; } af;
        af.u[0] = pk2(xa.x, xa.y);
        af.u[1] = pk2(xa.z, xa.w);
        af.u[2] = pk2(xb.x, xb.y);
        af.u[3] = pk2(xb.z, xb.w);
        #pragma unroll
        for (int nt = 0; nt < 8; ++nt) {
            union { uint4 v; short8 s; } bu;
            bu.v = Bp[(long)(ks * 8 + nt) * 64 + lane];
            acc[nt] = __builtin_amdgcn_mfma_f32_16x16x32_bf16(af.s, bu.s, acc[nt], 0, 0, 0);
        }
    }

    float dv[4];
    #pragma unroll
    for (int r = 0; r < 4; ++r) {
        int v = m0 + q * 4 + r;
        dv[r] = dinv[v > N_NODES - 1 ? N_NODES - 1 : v];
    }
    unsigned short* o = ot[wave];
    #pragma unroll
    for (int nt = 0; nt < 8; ++nt) {
        float bn = bf[nt * 16 + ml];
        #pragma unroll
        for (int r = 0; r < 4; ++r) {
            float val = dv[r] * (acc[nt][r] + bn);
            o[(q * 4 + r) * 128 + nt * 16 + ml] = f2bf(val);
        }
    }
    __syncthreads();
    #pragma unroll
    for (int i = 0; i < 4; ++i) {
        int fb = i * 1024 + lane * 16;
        int v = m0 + (fb >> 8);
        if (v < N_NODES) {
            uint4 val = *(const uint4*)((const char*)o + fb);
            *(uint4*)((char*)hsb + (long)v * 256 + (fb & 255)) = val;
        }
    }
}

// ---------------- bucket aggregation: LDS fp32 accumulators, no global atomics ----
__global__ __launch_bounds__(256) void bucket_aggregate_k(const int* __restrict__ boffs,
                                                          const unsigned int* __restrict__ eb,
                                                          const unsigned int* __restrict__ hs32,
                                                          const float* __restrict__ dinv,
                                                          const float* __restrict__ bc,
                                                          unsigned int* __restrict__ feat32) {
    __shared__ float acc[64 * 128];   // 32 KB
    int t = threadIdx.x;
    for (int i = t; i < 64 * 128; i += 256) acc[i] = 0.f;
    __syncthreads();
    int g = blockIdx.x;
    int s = boffs[g], e = boffs[g + 1];
    int wave = t >> 6, lane = t & 63;

    for (int ib = s + wave * 4; ib < e; ib += 16) {   // 4 edges in flight per wave
        int n = e - ib; if (n > 4) n = 4;
        if (n == 4) {
            unsigned int u0 = eb[ib], u1 = eb[ib + 1], u2 = eb[ib + 2], u3 = eb[ib + 3];
            unsigned int g0 = hs32[(long)(u0 & 0xFFFF) * 64 + lane];
            unsigned int g1 = hs32[(long)(u1 & 0xFFFF) * 64 + lane];
            unsigned int g2 = hs32[(long)(u2 & 0xFFFF) * 64 + lane];
            unsigned int g3 = hs32[(long)(u3 & 0xFFFF) * 64 + lane];
            int c0 = (u0 >> 16) & 63, c1 = (u1 >> 16) & 63, c2 = (u2 >> 16) & 63, c3 = (u3 >> 16) & 63;
            atomicAdd(&acc[c0 * 128 + 2 * lane], bflo(g0));
            atomicAdd(&acc[c0 * 128 + 2 * lane + 1], bfhi(g0));
            atomicAdd(&acc[c1 * 128 + 2 * lane], bflo(g1));
            atomicAdd(&acc[c1 * 128 + 2 * lane + 1], bfhi(g1));
            atomicAdd(&acc[c2 * 128 + 2 * lane], bflo(g2));
            atomicAdd(&acc[c2 * 128 + 2 * lane + 1], bfhi(g2));
            atomicAdd(&acc[c3 * 128 + 2 * lane], bflo(g3));
            atomicAdd(&acc[c3 * 128 + 2 * lane + 1], bfhi(g3));
        } else {
            for (int k = 0; k < n; ++k) {
                unsigned int u = eb[ib + k];
                unsigned int gv = hs32[(long)(u & 0xFFFF) * 64 + lane];
                int cl = (u >> 16) & 63;
                atomicAdd(&acc[cl * 128 + 2 * lane], bflo(gv));
                atomicAdd(&acc[cl * 128 + 2 * lane + 1], bfhi(gv));
            }
        }
    }
    __syncthreads();
    // finalize: feat = dinv*(acc + self) + bc
    int v0 = g * 64;
    for (int i = t; i < 64 * 64; i += 256) {
        int nl = i >> 6, l = i & 63;
        int v = v0 + nl;
        if (v < N_NODES) {
            unsigned int su = hs32[(long)v * 64 + l];
            float dv = dinv[v];
            float f0 = dv * (acc[nl * 128 + 2 * l] + bflo(su)) + bc[2 * l];
            float f1 = dv * (acc[nl * 128 + 2 * l + 1] + bfhi(su)) + bc[2 * l + 1];
            feat32[(long)v * 64 + l] = pk2(f0, f1);
        }
    }
}

// ---------------- logits[e] = dot(feat[src], feat[dst]) — 16 lanes/edge ----------------
__global__ void score_k(const int* __restrict__ src, const int* __restrict__ dst,
                        const uint4* __restrict__ feat4, float* __restrict__ out) {
    int gid = blockIdx.x * blockDim.x + threadIdx.x;
    int e = gid >> 4;
    int c = gid & 15;
    if (e >= N_PRED) return;
    int a = src[e], b = dst[e];
    uint4 ua = feat4[(long)a * 16 + c];
    uint4 ub = feat4[(long)b * 16 + c];
    float p = bflo(ua.x) * bflo(ub.x) + bfhi(ua.x) * bfhi(ub.x)
            + bflo(ua.y) * bflo(ub.y) + bfhi(ua.y) * bfhi(ub.y)
            + bflo(ua.z) * bflo(ub.z) + bfhi(ua.z) * bfhi(ub.z)
            + bflo(ua.w) * bflo(ub.w) + bfhi(ua.w) * bfhi(ub.w);
    #pragma unroll
    for (int m = 8; m; m >>= 1) p += __shfl_xor(p, m, 16);
    if (c == 0) out[e] = p;
}

extern "C" void kernel_launch(void* const* d_in, const int* in_sizes, int n_in,
                              void* d_out, int out_size, void* d_ws, size_t ws_size,
                              hipStream_t stream) {
    const float* x   = (const float*)d_in[0];
    const int*   ei  = (const int*)  d_in[1];   // [2, N_PRED]
    const int*   pe  = (const int*)  d_in[2];   // [2, N_POS]
    const float* W1  = (const float*)d_in[3];
    const float* b1  = (const float*)d_in[4];
    const float* Wc  = (const float*)d_in[5];
    const float* bc  = (const float*)d_in[6];
    float* out = (float*)d_out;

    const int* pe_row = pe;            // source
    const int* pe_col = pe + N_POS;    // target (aggregation)
    const int* ei_src = ei;
    const int* ei_dst = ei + N_PRED;

    // workspace layout (16B-aligned blocks)
    char* w = (char*)d_ws;
    unsigned short* Bp = (unsigned short*)w;  w += 32768 * 2;      // 64 KB
    float* bf    = (float*)w;                 w += 128 * 4;
    float* dinv  = (float*)w;                 w += 50000 * 4;
    int*   cnt   = (int*)w;                   w += 50000 * 4;      // cnt then bcnt adjacent
    int*   bcnt  = (int*)w;                   w += GPAD * 4;
    int*   boffs = (int*)w;                   w += (GPAD + 4) * 4;
    int*   bfill = (int*)w;                   w += GPAD * 4;
    unsigned int* eb = (unsigned int*)w;      w += (long)N_POS * 4;            // 6.4 MB
    unsigned short* hsb   = (unsigned short*)w;  w += (long)N_NODES * D_OUT * 2; // 12.8 MB
    unsigned short* featb = (unsigned short*)w;  // 12.8 MB

    // degrees + dinv
    zero_int_k   <<<(50000 + GPAD + 255) / 256, 256, 0, stream>>>(cnt, 50000 + GPAD);
    count_k      <<<(N_POS + 255) / 256, 256, 0, stream>>>(pe_col, cnt);
    dinv_k       <<<(N_NODES + 255) / 256, 256, 0, stream>>>(cnt, dinv);

    // bucket partition of edges by target
    bucket_count_k  <<<SB, 256, 0, stream>>>(pe_col, bcnt);
    scan_bucket_k   <<<1, 1024, 0, stream>>>(bcnt, boffs, bfill);
    bucket_scatter_k<<<SB, 256, 0, stream>>>(pe_row, pe_col, bfill, eb);

    // dense pipeline (MFMA)
    fuse_weights_k<<<128, 256, 0, stream>>>(W1, Wc, b1, Bp, bf);
    gemm_mfma_k   <<<(N_NODES + 63) / 64, 256, 0, stream>>>(x, (const uint4*)Bp, bf, dinv, hsb);

    // aggregation + finalize (LDS accumulators, no global atomics)
    bucket_aggregate_k<<<G_BUCKETS, 256, 0, stream>>>(boffs, eb, (const unsigned int*)hsb,
                                                      dinv, bc, (unsigned int*)featb);

    // scoring
    score_k       <<<(int)(((long)N_PRED * 16) / 256), 256, 0, stream>>>(
                      ei_src, ei_dst, (const uint4*)featb, out);
}

// Round 6
// 297.617 us; speedup vs baseline: 5.5577x; 5.5577x over previous
//
#include <hip/hip_runtime.h>

#define N_NODES 50000
#define D_IN 256
#define D_OUT 128
#define N_POS 1600000
#define N_PRED 500000

#define G_BUCKETS 782        // ceil(50000/64) buckets of 64 nodes
#define GPAD 1024
#define SB 160               // scatter blocks
#define CHUNK 10000          // SB*CHUNK == N_POS exactly
#define CAP 4096             // max edges per bucket (mean 2048, sigma 45 -> 45-sigma margin)

typedef __attribute__((ext_vector_type(8))) short short8;
typedef __attribute__((ext_vector_type(4))) float f32x4;

// ---- bf16 helpers (RNE) ----
__device__ __forceinline__ unsigned short f2bf(float f) {
    unsigned int u = __float_as_uint(f);
    u += 0x7FFFu + ((u >> 16) & 1u);
    return (unsigned short)(u >> 16);
}
__device__ __forceinline__ unsigned int pk2(float a, float b) {   // bf16(a) | bf16(b)<<16
    unsigned int ua = __float_as_uint(a), ub = __float_as_uint(b);
    ua += 0x7FFFu + ((ua >> 16) & 1u);
    ub += 0x7FFFu + ((ub >> 16) & 1u);
    return (ua >> 16) | (ub & 0xFFFF0000u);
}
__device__ __forceinline__ float bflo(unsigned int u) { return __uint_as_float(u << 16); }
__device__ __forceinline__ float bfhi(unsigned int u) { return __uint_as_float(u & 0xFFFF0000u); }

// ------- Wf = W1@Wc packed into MFMA B-fragment layout; bf = b1@Wc -------
__global__ void fuse_weights_k(const float* __restrict__ W1, const float* __restrict__ Wc,
                               const float* __restrict__ b1,
                               unsigned short* __restrict__ Bp, float* __restrict__ bf) {
    int gid = blockIdx.x * blockDim.x + threadIdx.x;   // 0..32767
    int k = gid >> 7;          // K dim
    int n = gid & 127;         // N dim
    float acc = 0.f;
    #pragma unroll 4
    for (int kk = 0; kk < D_IN; ++kk)
        acc += W1[k * D_IN + kk] * Wc[kk * D_OUT + n];
    int ks = k >> 5, q = (k >> 3) & 3, jj = k & 7;
    int nt = n >> 4, nl = n & 15;
    int lane = q * 16 + nl;
    Bp[(((long)(ks * 8 + nt)) * 64 + lane) * 8 + jj] = f2bf(acc);
    if (gid < D_OUT) {
        float accb = 0.f;
        for (int kk = 0; kk < D_IN; ++kk)
            accb += b1[kk] * Wc[kk * D_OUT + gid];
        bf[gid] = accb;
    }
}

__global__ void zero_int_k(int* __restrict__ p, int n) {
    int i = blockIdx.x * blockDim.x + threadIdx.x;
    if (i < n) p[i] = 0;
}

// ---------------- bucket partition ----------------
__global__ __launch_bounds__(256) void bucket_count_k(const int* __restrict__ col,
                                                      int* __restrict__ bcnt) {
    __shared__ int hist[GPAD];
    int t = threadIdx.x;
    for (int i = t; i < GPAD; i += 256) hist[i] = 0;
    __syncthreads();
    int e0 = blockIdx.x * CHUNK;
    for (int i = t; i < CHUNK; i += 256)
        atomicAdd(&hist[col[e0 + i] >> 6], 1);
    __syncthreads();
    for (int g = t; g < G_BUCKETS; g += 256) {
        int c = hist[g];
        if (c) atomicAdd(&bcnt[g], c);
    }
}

__global__ __launch_bounds__(1024) void scan_bucket_k(const int* __restrict__ bcnt,
                                                      int* __restrict__ boffs,
                                                      int* __restrict__ bfill,
                                                      int* __restrict__ offs) {
    __shared__ int s[1024];
    int t = threadIdx.x;
    int v = (t < G_BUCKETS) ? bcnt[t] : 0;
    s[t] = v;
    __syncthreads();
    for (int d = 1; d < 1024; d <<= 1) {
        int add = (t >= d) ? s[t - d] : 0;
        __syncthreads();
        s[t] += add;
        __syncthreads();
    }
    int ex = s[t] - v;
    if (t < G_BUCKETS) { boffs[t] = ex; bfill[t] = ex; }
    if (t == G_BUCKETS - 1) boffs[G_BUCKETS] = ex + v;
    if (t == 0) offs[N_NODES] = N_POS;
}

// bin chunk edges by bucket in LDS, write out bucket-contiguous bursts
__global__ __launch_bounds__(256) void bucket_scatter_k(const int* __restrict__ row,
                                                        const int* __restrict__ col,
                                                        int* __restrict__ bfill,
                                                        unsigned int* __restrict__ eb) {
    __shared__ int hist[GPAD];
    __shared__ int lofs[GPAD];
    __shared__ int fill2[GPAD];
    __shared__ int base[GPAD];
    __shared__ int part[256];
    __shared__ unsigned int stag[CHUNK];
    int t = threadIdx.x;
    for (int i = t; i < GPAD; i += 256) { hist[i] = 0; fill2[i] = 0; }
    __syncthreads();
    int e0 = blockIdx.x * CHUNK;
    for (int i = t; i < CHUNK; i += 256)
        atomicAdd(&hist[col[e0 + i] >> 6], 1);
    __syncthreads();
    int h[4], p4 = 0;
    #pragma unroll
    for (int i = 0; i < 4; ++i) { h[i] = hist[4 * t + i]; p4 += h[i]; }
    part[t] = p4;
    __syncthreads();
    for (int d = 1; d < 256; d <<= 1) {
        int add = (t >= d) ? part[t - d] : 0;
        __syncthreads();
        part[t] += add;
        __syncthreads();
    }
    int ex = part[t] - p4;
    #pragma unroll
    for (int i = 0; i < 4; ++i) { lofs[4 * t + i] = ex; ex += h[i]; }
    __syncthreads();
    for (int g = t; g < G_BUCKETS; g += 256) {
        int c = hist[g];
        base[g] = c ? atomicAdd(&bfill[g], c) : 0;
    }
    for (int i = t; i < CHUNK; i += 256) {
        int c = col[e0 + i];
        int g = c >> 6;
        unsigned int u = (unsigned int)row[e0 + i] | ((unsigned int)(c & 63) << 16)
                       | ((unsigned int)g << 22);
        int lp = atomicAdd(&fill2[g], 1);
        stag[lofs[g] + lp] = u;
    }
    __syncthreads();
    for (int i = t; i < CHUNK; i += 256) {
        unsigned int u = stag[i];
        int g = u >> 22;
        eb[base[g] + (i - lofs[g])] = u;
    }
}

// ---- per-bucket CSR build: node-sorted rows, contiguous writes; emits offs + dinv ----
__global__ __launch_bounds__(256) void csr_build_k(const int* __restrict__ boffs,
                                                   const unsigned int* __restrict__ eb,
                                                   int* __restrict__ csr,
                                                   int* __restrict__ offs,
                                                   float* __restrict__ dinv) {
    __shared__ unsigned int stag[CAP];
    __shared__ unsigned short stag2[CAP];
    __shared__ int hist[64], lofs[64], fill[64];
    int t = threadIdx.x;
    int g = blockIdx.x;
    int s = boffs[g], e = boffs[g + 1];
    int cnt = e - s;
    if (t < 64) { hist[t] = 0; fill[t] = 0; }
    __syncthreads();
    for (int i = t; i < cnt; i += 256) {
        unsigned int u = eb[s + i];
        stag[i] = u;
        atomicAdd(&hist[(u >> 16) & 63], 1);
    }
    __syncthreads();
    if (t == 0) {
        int run = 0;
        for (int k = 0; k < 64; ++k) { lofs[k] = run; run += hist[k]; }
    }
    __syncthreads();
    if (t < 64) {
        int v = g * 64 + t;
        if (v < N_NODES) {
            offs[v] = s + lofs[t];
            dinv[v] = rsqrtf((float)hist[t] + 1.0f);   // +1 self loop
        }
    }
    for (int i = t; i < cnt; i += 256) {
        unsigned int u = stag[i];
        int nl = (u >> 16) & 63;
        int lp = atomicAdd(&fill[nl], 1);
        stag2[lofs[nl] + lp] = (unsigned short)(u & 0xFFFF);
    }
    __syncthreads();
    for (int i = t; i < cnt; i += 256)
        csr[s + i] = (int)stag2[i];
}

// ---------------- MFMA GEMM: hs = bf16( dinv[v] * (x @ Wf + bf) ) ----------------
__global__ __launch_bounds__(256) void gemm_mfma_k(const float* __restrict__ x,
                                                   const uint4* __restrict__ Bp,
                                                   const float* __restrict__ bf,
                                                   const float* __restrict__ dinv,
                                                   unsigned short* __restrict__ hsb) {
    __shared__ unsigned short ot[4][16 * 128];   // 16 KB epilogue staging
    const int wave = threadIdx.x >> 6;
    const int lane = threadIdx.x & 63;
    const int q    = lane >> 4;
    const int ml   = lane & 15;
    const int m0   = blockIdx.x * 64 + wave * 16;

    f32x4 acc[8];
    #pragma unroll
    for (int t = 0; t < 8; ++t) acc[t] = (f32x4){0.f, 0.f, 0.f, 0.f};

    long arow = m0 + ml; if (arow > N_NODES - 1) arow = N_NODES - 1;
    const float* xrow = x + arow * D_IN + q * 8;

    #pragma unroll
    for (int ks = 0; ks < 8; ++ks) {
        float4 xa = *(const float4*)(xrow + ks * 32);
        float4 xb = *(const float4*)(xrow + ks * 32 + 4);
        union { short8 s; unsigned int u[4]; } af;
        af.u[0] = pk2(xa.x, xa.y);
        af.u[1] = pk2(xa.z, xa.w);
        af.u[2] = pk2(xb.x, xb.y);
        af.u[3] = pk2(xb.z, xb.w);
        #pragma unroll
        for (int nt = 0; nt < 8; ++nt) {
            union { uint4 v; short8 s; } bu;
            bu.v = Bp[(long)(ks * 8 + nt) * 64 + lane];
            acc[nt] = __builtin_amdgcn_mfma_f32_16x16x32_bf16(af.s, bu.s, acc[nt], 0, 0, 0);
        }
    }

    float dv[4];
    #pragma unroll
    for (int r = 0; r < 4; ++r) {
        int v = m0 + q * 4 + r;
        dv[r] = dinv[v > N_NODES - 1 ? N_NODES - 1 : v];
    }
    unsigned short* o = ot[wave];
    #pragma unroll
    for (int nt = 0; nt < 8; ++nt) {
        float bn = bf[nt * 16 + ml];
        #pragma unroll
        for (int r = 0; r < 4; ++r) {
            float val = dv[r] * (acc[nt][r] + bn);
            o[(q * 4 + r) * 128 + nt * 16 + ml] = f2bf(val);
        }
    }
    __syncthreads();
    #pragma unroll
    for (int i = 0; i < 4; ++i) {
        int fb = i * 1024 + lane * 16;
        int v = m0 + (fb >> 8);
        if (v < N_NODES) {
            uint4 val = *(const uint4*)((const char*)o + fb);
            *(uint4*)((char*)hsb + (long)v * 256 + (fb & 255)) = val;
        }
    }
}

// ---------------- per-node CSR aggregation + finalize (bf16 table, fp32 accum) ----
__global__ __launch_bounds__(256) void aggregate_csr_k(const int* __restrict__ offs,
                                                       const int* __restrict__ csr,
                                                       const unsigned int* __restrict__ hs32,
                                                       const float* __restrict__ dinv,
                                                       const float* __restrict__ bc,
                                                       unsigned int* __restrict__ feat32) {
    int v    = blockIdx.x * 4 + (threadIdx.x >> 6);
    int lane = threadIdx.x & 63;
    int s = offs[v], e = offs[v + 1];

    unsigned int u = hs32[(long)v * 64 + lane];   // self-loop term
    float a0 = bflo(u), a1 = bfhi(u);
    int i = s;
    for (; i + 4 <= e; i += 4) {
        int r0 = csr[i], r1 = csr[i + 1], r2 = csr[i + 2], r3 = csr[i + 3];
        unsigned int u0 = hs32[(long)r0 * 64 + lane];
        unsigned int u1 = hs32[(long)r1 * 64 + lane];
        unsigned int u2 = hs32[(long)r2 * 64 + lane];
        unsigned int u3 = hs32[(long)r3 * 64 + lane];
        a0 += bflo(u0) + bflo(u1) + bflo(u2) + bflo(u3);
        a1 += bfhi(u0) + bfhi(u1) + bfhi(u2) + bfhi(u3);
    }
    for (; i < e; ++i) {
        unsigned int uu = hs32[(long)csr[i] * 64 + lane];
        a0 += bflo(uu); a1 += bfhi(uu);
    }

    float dv = dinv[v];
    float f0 = dv * a0 + bc[2 * lane];
    float f1 = dv * a1 + bc[2 * lane + 1];
    feat32[(long)v * 64 + lane] = pk2(f0, f1);
}

// ---------------- logits[e] = dot(feat[src], feat[dst]) — 16 lanes/edge ----------------
__global__ void score_k(const int* __restrict__ src, const int* __restrict__ dst,
                        const uint4* __restrict__ feat4, float* __restrict__ out) {
    int gid = blockIdx.x * blockDim.x + threadIdx.x;
    int e = gid >> 4;
    int c = gid & 15;
    if (e >= N_PRED) return;
    int a = src[e], b = dst[e];
    uint4 ua = feat4[(long)a * 16 + c];
    uint4 ub = feat4[(long)b * 16 + c];
    float p = bflo(ua.x) * bflo(ub.x) + bfhi(ua.x) * bfhi(ub.x)
            + bflo(ua.y) * bflo(ub.y) + bfhi(ua.y) * bfhi(ub.y)
            + bflo(ua.z) * bflo(ub.z) + bfhi(ua.z) * bfhi(ub.z)
            + bflo(ua.w) * bflo(ub.w) + bfhi(ua.w) * bfhi(ub.w);
    #pragma unroll
    for (int m = 8; m; m >>= 1) p += __shfl_xor(p, m, 16);
    if (c == 0) out[e] = p;
}

extern "C" void kernel_launch(void* const* d_in, const int* in_sizes, int n_in,
                              void* d_out, int out_size, void* d_ws, size_t ws_size,
                              hipStream_t stream) {
    const float* x   = (const float*)d_in[0];
    const int*   ei  = (const int*)  d_in[1];   // [2, N_PRED]
    const int*   pe  = (const int*)  d_in[2];   // [2, N_POS]
    const float* W1  = (const float*)d_in[3];
    const float* b1  = (const float*)d_in[4];
    const float* Wc  = (const float*)d_in[5];
    const float* bc  = (const float*)d_in[6];
    float* out = (float*)d_out;

    const int* pe_row = pe;            // source
    const int* pe_col = pe + N_POS;    // target (aggregation)
    const int* ei_src = ei;
    const int* ei_dst = ei + N_PRED;

    // workspace layout (16B-aligned blocks)
    char* w = (char*)d_ws;
    unsigned short* Bp = (unsigned short*)w;  w += 32768 * 2;      // 64 KB
    float* bf    = (float*)w;                 w += 128 * 4;
    float* dinv  = (float*)w;                 w += 50000 * 4;
    int*   bcnt  = (int*)w;                   w += GPAD * 4;
    int*   boffs = (int*)w;                   w += (GPAD + 4) * 4;
    int*   bfill = (int*)w;                   w += GPAD * 4;
    int*   offs  = (int*)w;                   w += 50004 * 4;      // [N+1] padded
    unsigned int* eb = (unsigned int*)w;      w += (long)N_POS * 4;            // 6.4 MB
    int*   csr   = (int*)w;                   w += (long)N_POS * 4;            // 6.4 MB
    unsigned short* hsb   = (unsigned short*)w;  w += (long)N_NODES * D_OUT * 2; // 12.8 MB
    unsigned short* featb = (unsigned short*)w;  // 12.8 MB

    // bucket partition of edges by target + CSR build (contiguous writes only)
    zero_int_k      <<<4, 256, 0, stream>>>(bcnt, GPAD);
    bucket_count_k  <<<SB, 256, 0, stream>>>(pe_col, bcnt);
    scan_bucket_k   <<<1, 1024, 0, stream>>>(bcnt, boffs, bfill, offs);
    bucket_scatter_k<<<SB, 256, 0, stream>>>(pe_row, pe_col, bfill, eb);
    csr_build_k     <<<G_BUCKETS, 256, 0, stream>>>(boffs, eb, csr, offs, dinv);

    // dense pipeline (MFMA)
    fuse_weights_k<<<128, 256, 0, stream>>>(W1, Wc, b1, Bp, bf);
    gemm_mfma_k   <<<(N_NODES + 63) / 64, 256, 0, stream>>>(x, (const uint4*)Bp, bf, dinv, hsb);

    // aggregation + finalize (no atomics, per-node waves)
    aggregate_csr_k<<<N_NODES / 4, 256, 0, stream>>>(offs, csr, (const unsigned int*)hsb,
                                                     dinv, bc, (unsigned int*)featb);

    // scoring
    score_k       <<<(int)(((long)N_PRED * 16) / 256), 256, 0, stream>>>(
                      ei_src, ei_dst, (const uint4*)featb, out);
}